// Round 8
// baseline (341.821 us; speedup 1.0000x reference)
//
#include <hip/hip_runtime.h>
#include <hip/hip_fp16.h>

// adj[b] = tanh(relu(E_b @ E_b^T)) + 0.5*I
// R14 = DIAGNOSTIC build of R13. Seven structural variants (R6..R13) are all
// neutral at kernel ~100-112 us vs a ~70 us serial model; the gram kernel has
// never surfaced in the rocprof top-5 (fills ~175 us dominate), so we have NO
// direct counters. This round runs the R13 body TWICE per dispatch:
//   pass 0: tile l            pass 1: tile (l + 561) % 1122  (same XCD,
//   other batch -> far-away addresses -> full HBM traffic both passes)
// Every tile is written exactly twice with byte-identical values (benign
// same-value overlap between different WGs) -> output correct; dispatch
// duration ~2x kernel (~208 us) > fill (~175 us) -> top-1 in the counter
// table WITH FETCH_SIZE / WRITE_SIZE / VALUBusy / MfmaUtil / Occupancy /
// VGPR. Composite dur will be ~385 us BY DESIGN; we are buying counters.
// Body is byte-identical R13 otherwise (full-line stores, one tile shape).

#define B_BATCH   16
#define N_SPATIAL 2048
#define T_TEMP    64
#define M_NODES   2112     // 33 * 64
#define D_FEAT    64
#define TILE      64
#define LDSK      72       // fp16 k-stride (+8 pad)
#define CSTR      68       // fp32 epilogue tile stride (+4 pad)

#define GROUPS_PER_STRIP 17
#define WGS_PER_BATCH    (33 * GROUPS_PER_STRIP)   // 561
#define TILES_PER_XCD    (2 * WGS_PER_BATCH)       // 1122
#define TOTAL_WGS        (WGS_PER_BATCH * B_BATCH) // 8976 = 8 * 1122

typedef _Float16 f16x8 __attribute__((ext_vector_type(8)));
typedef float    f32x4 __attribute__((ext_vector_type(4)));

__device__ __forceinline__ f16x8 cvt2(const float4* p) {
    float4 a = p[0], c = p[1];
    f16x8 h;
    h[0] = (_Float16)a.x; h[1] = (_Float16)a.y;
    h[2] = (_Float16)a.z; h[3] = (_Float16)a.w;
    h[4] = (_Float16)c.x; h[5] = (_Float16)c.y;
    h[6] = (_Float16)c.z; h[7] = (_Float16)c.w;
    return h;
}

__global__ __launch_bounds__(256, 3)
void gram_tanh_mfma(const float* __restrict__ sp,
                    const float* __restrict__ tp,
                    float* __restrict__ out)
{
    const int lin = blockIdx.x;
    const int xcd = lin & 7;
    const int l   = lin >> 3;            // 0..1121 within XCD

    __shared__ __align__(16) _Float16 As[TILE][LDSK];       //  9216 B
    __shared__ __align__(16) _Float16 Bs[2][TILE][LDSK];    // 18432 B
    __shared__ __align__(16) float    Ct[TILE][CSTR];       // 17408 B -> 45056 B

    const int tid  = threadIdx.x;
    const int wave = tid >> 6;
    const int lane = tid & 63;
    const int lr   = lane & 15;
    const int q    = lane >> 4;

    #pragma unroll 1
    for (int pass = 0; pass < 2; ++pass) {
        // pass 0: own tile; pass 1: same-XCD other-batch tile (far output)
        int lp = l + (pass ? WGS_PER_BATCH : 0);
        if (lp >= TILES_PER_XCD) lp -= TILES_PER_XCD;

        const int bo  = lp / WGS_PER_BATCH;             // 0,1
        const int rr  = lp - bo * WGS_PER_BATCH;
        const int ti  = rr / GROUPS_PER_STRIP;          // 0..32
        const int g   = rr - ti * GROUPS_PER_STRIP;     // 0..16
        const int b   = 2 * xcd + bo;
        const int tj0 = 2 * g;
        const bool have2 = (tj0 + 1 < 33);
        const int tj1 = have2 ? tj0 + 1 : 32;

        __syncthreads();   // protect LDS overwrite vs prev pass readers

        // ---- stage + convert fp32 -> fp16 ----
        {
            const int row = tid >> 2;
            const int kb  = (tid & 3) * 16;
            const float* srcA = (ti < 32)
                ? sp + ((size_t)b * N_SPATIAL + (size_t)ti * TILE) * D_FEAT
                : tp + (size_t)b * T_TEMP * D_FEAT;
            const float* srcB0 = (tj0 < 32)
                ? sp + ((size_t)b * N_SPATIAL + (size_t)tj0 * TILE) * D_FEAT
                : tp + (size_t)b * T_TEMP * D_FEAT;
            const float* srcB1 = (tj1 < 32)
                ? sp + ((size_t)b * N_SPATIAL + (size_t)tj1 * TILE) * D_FEAT
                : tp + (size_t)b * T_TEMP * D_FEAT;
            const float4* pa  = (const float4*)(srcA  + (size_t)row * D_FEAT + kb);
            const float4* pb0 = (const float4*)(srcB0 + (size_t)row * D_FEAT + kb);
            const float4* pb1 = (const float4*)(srcB1 + (size_t)row * D_FEAT + kb);

            *(f16x8*)&As[row][kb]        = cvt2(pa);
            *(f16x8*)&As[row][kb + 8]    = cvt2(pa + 2);
            *(f16x8*)&Bs[0][row][kb]     = cvt2(pb0);
            *(f16x8*)&Bs[0][row][kb + 8] = cvt2(pb0 + 2);
            *(f16x8*)&Bs[1][row][kb]     = cvt2(pb1);
            *(f16x8*)&Bs[1][row][kb + 8] = cvt2(pb1 + 2);
        }
        __syncthreads();

        // ---- MFMA ----
        f32x4 acc[2][4];
        #pragma unroll
        for (int n = 0; n < 2; ++n)
            #pragma unroll
            for (int tt = 0; tt < 4; ++tt) acc[n][tt] = (f32x4){0.f, 0.f, 0.f, 0.f};

        #pragma unroll
        for (int s = 0; s < 2; ++s) {                 // K = 64 = 2 x 32
            f16x8 afrag = *(const f16x8*)&As[wave * 16 + lr][s * 32 + q * 8];
            #pragma unroll
            for (int n = 0; n < 2; ++n) {
                #pragma unroll
                for (int tt = 0; tt < 4; ++tt) {
                    f16x8 bfrag = *(const f16x8*)&Bs[n][tt * 16 + lr][s * 32 + q * 8];
                    acc[n][tt] = __builtin_amdgcn_mfma_f32_16x16x32_f16(afrag, bfrag, acc[n][tt], 0, 0, 0);
                }
            }
        }

        // ---- epilogue: tanh(relu)+diag -> wave-private Ct -> full-line stores
        #pragma unroll
        for (int n = 0; n < 2; ++n) {
            if (n == 1 && !have2) break;              // wave-uniform skip
            const int tjn = n ? tj1 : tj0;
            const bool diagT = (ti == tjn);
            #pragma unroll
            for (int tt = 0; tt < 4; ++tt) {
                const int col = tt * 16 + lr;
                #pragma unroll
                for (int i = 0; i < 4; ++i) {
                    const int row = wave * 16 + q * 4 + i;
                    float x = fmaxf(acc[n][tt][i], 0.f);
                    float e = __expf(2.f * x);
                    float v = 1.f - 2.f * __builtin_amdgcn_rcpf(e + 1.f);
                    if (diagT && (row == col)) v += 0.5f;
                    Ct[row][col] = v;
                }
            }
            // in-wave LDS ordering via lgkmcnt; wave-private rows, no sync.
            // Full-line stores: 8 rows x 128 B per instruction.
            const int rs = lane >> 3;                 // 0..7
            #pragma unroll
            for (int rh = 0; rh < 2; ++rh) {
                const int r_loc = wave * 16 + rh * 8 + rs;
                float* dst = out + (size_t)b * M_NODES * M_NODES
                                 + (size_t)(ti * TILE + r_loc) * M_NODES
                                 + tjn * TILE;
                #pragma unroll
                for (int u = 0; u < 2; ++u) {
                    const int c4 = (lane & 7) * 4 + 32 * u;
                    *(float4*)(dst + c4) = *(const float4*)&Ct[r_loc][c4];
                }
            }
        }
    }
}

extern "C" void kernel_launch(void* const* d_in, const int* in_sizes, int n_in,
                              void* d_out, int out_size, void* d_ws, size_t ws_size,
                              hipStream_t stream) {
    const float* sp = (const float*)d_in[0];   // [16, 2048, 64] fp32
    const float* tp = (const float*)d_in[1];   // [16, 64, 64]   fp32
    float* out = (float*)d_out;                // [16, 2112, 2112] fp32

    dim3 grid(TOTAL_WGS);                      // 8976; kernel does XCD decode
    dim3 block(256);
    hipLaunchKernelGGL(gram_tanh_mfma, grid, block, 0, stream, sp, tp, out);
}

// Round 9
// 289.499 us; speedup vs baseline: 1.1807x; 1.1807x over previous
//
#include <hip/hip_runtime.h>
#include <hip/hip_fp16.h>

// adj[b] = tanh(relu(E_b @ E_b^T)) + 0.5*I
// E_b = concat(spatial[b] (2048x64), temporal[b] (64x64)) fp32 -> fp16 MFMA,
// fp32 accumulate. Output: [16, 2112, 2112] fp32.
// R15: multi-tile WGs, calibrated by the R14 diagnostic.
//   R13 (1 tile/WG): kernel ~103 us -> per-WG cost o+w   = 8.8 us
//   R14 (2 tiles/WG, dup): ~148 us  -> per-WG cost o+2w  = 12.7 us
//   => marginal tile w = 3.85 us (= HBM write floor share, 45 us aggregate);
//      fixed per-WG overhead o = 5 us (58 us aggregate at 1 tile/WG!).
// Fix: amortize o. Each WG runs the BYTE-IDENTICAL R14 loop body over
// k=6 DISTINCT tiles (lp = w0 + j*187; 1122 = 6*187 exactly).
// Grid 1496 = 187*8 (XCD round-robin preserved). Model: wall = 1496 *
// (o+6w)/768 ~ 55 us -> composite ~230-250. NO other change (R11's
// persistent variant failed via a different body -- prefetch reg pressure).

#define B_BATCH   16
#define N_SPATIAL 2048
#define T_TEMP    64
#define M_NODES   2112     // 33 * 64
#define D_FEAT    64
#define TILE      64
#define LDSK      72       // fp16 k-stride (+8 pad)
#define CSTR      68       // fp32 epilogue tile stride (+4 pad)

#define GROUPS_PER_STRIP 17
#define WGS_PER_BATCH    (33 * GROUPS_PER_STRIP)   // 561 tiles/batch
#define TILES_PER_XCD    (2 * WGS_PER_BATCH)       // 1122
#define TILES_PER_WG     6
#define WG_STRIDE        (TILES_PER_XCD / TILES_PER_WG)  // 187
#define TOTAL_WGS        (WG_STRIDE * 8)           // 1496

typedef _Float16 f16x8 __attribute__((ext_vector_type(8)));
typedef float    f32x4 __attribute__((ext_vector_type(4)));

__device__ __forceinline__ f16x8 cvt2(const float4* p) {
    float4 a = p[0], c = p[1];
    f16x8 h;
    h[0] = (_Float16)a.x; h[1] = (_Float16)a.y;
    h[2] = (_Float16)a.z; h[3] = (_Float16)a.w;
    h[4] = (_Float16)c.x; h[5] = (_Float16)c.y;
    h[6] = (_Float16)c.z; h[7] = (_Float16)c.w;
    return h;
}

__global__ __launch_bounds__(256, 3)
void gram_tanh_mfma(const float* __restrict__ sp,
                    const float* __restrict__ tp,
                    float* __restrict__ out)
{
    const int lin = blockIdx.x;
    const int xcd = lin & 7;
    const int w0  = lin >> 3;            // 0..186 within XCD

    __shared__ __align__(16) _Float16 As[TILE][LDSK];       //  9216 B
    __shared__ __align__(16) _Float16 Bs[2][TILE][LDSK];    // 18432 B
    __shared__ __align__(16) float    Ct[TILE][CSTR];       // 17408 B -> 45056 B

    const int tid  = threadIdx.x;
    const int wave = tid >> 6;
    const int lane = tid & 63;
    const int lr   = lane & 15;
    const int q    = lane >> 4;

    #pragma unroll 1
    for (int j = 0; j < TILES_PER_WG; ++j) {
        const int lp = w0 + j * WG_STRIDE;              // 0..1121, all distinct

        const int bo  = lp / WGS_PER_BATCH;             // 0,1
        const int rr  = lp - bo * WGS_PER_BATCH;
        const int ti  = rr / GROUPS_PER_STRIP;          // 0..32
        const int g   = rr - ti * GROUPS_PER_STRIP;     // 0..16
        const int b   = 2 * xcd + bo;
        const int tj0 = 2 * g;
        const bool have2 = (tj0 + 1 < 33);
        const int tj1 = have2 ? tj0 + 1 : 32;

        __syncthreads();   // protect LDS overwrite vs prev iter readers

        // ---- stage + convert fp32 -> fp16 ----
        {
            const int row = tid >> 2;
            const int kb  = (tid & 3) * 16;
            const float* srcA = (ti < 32)
                ? sp + ((size_t)b * N_SPATIAL + (size_t)ti * TILE) * D_FEAT
                : tp + (size_t)b * T_TEMP * D_FEAT;
            const float* srcB0 = (tj0 < 32)
                ? sp + ((size_t)b * N_SPATIAL + (size_t)tj0 * TILE) * D_FEAT
                : tp + (size_t)b * T_TEMP * D_FEAT;
            const float* srcB1 = (tj1 < 32)
                ? sp + ((size_t)b * N_SPATIAL + (size_t)tj1 * TILE) * D_FEAT
                : tp + (size_t)b * T_TEMP * D_FEAT;
            const float4* pa  = (const float4*)(srcA  + (size_t)row * D_FEAT + kb);
            const float4* pb0 = (const float4*)(srcB0 + (size_t)row * D_FEAT + kb);
            const float4* pb1 = (const float4*)(srcB1 + (size_t)row * D_FEAT + kb);

            *(f16x8*)&As[row][kb]        = cvt2(pa);
            *(f16x8*)&As[row][kb + 8]    = cvt2(pa + 2);
            *(f16x8*)&Bs[0][row][kb]     = cvt2(pb0);
            *(f16x8*)&Bs[0][row][kb + 8] = cvt2(pb0 + 2);
            *(f16x8*)&Bs[1][row][kb]     = cvt2(pb1);
            *(f16x8*)&Bs[1][row][kb + 8] = cvt2(pb1 + 2);
        }
        __syncthreads();

        // ---- MFMA: wave w -> rows [16w,16w+16) x 2 sub-tiles of 64 cols ----
        f32x4 acc[2][4];
        #pragma unroll
        for (int n = 0; n < 2; ++n)
            #pragma unroll
            for (int tt = 0; tt < 4; ++tt) acc[n][tt] = (f32x4){0.f, 0.f, 0.f, 0.f};

        #pragma unroll
        for (int s = 0; s < 2; ++s) {                 // K = 64 = 2 x 32
            f16x8 afrag = *(const f16x8*)&As[wave * 16 + lr][s * 32 + q * 8];
            #pragma unroll
            for (int n = 0; n < 2; ++n) {
                #pragma unroll
                for (int tt = 0; tt < 4; ++tt) {
                    f16x8 bfrag = *(const f16x8*)&Bs[n][tt * 16 + lr][s * 32 + q * 8];
                    acc[n][tt] = __builtin_amdgcn_mfma_f32_16x16x32_f16(afrag, bfrag, acc[n][tt], 0, 0, 0);
                }
            }
        }

        // ---- epilogue: tanh(relu)+diag -> wave-private Ct -> full-line stores
        #pragma unroll
        for (int n = 0; n < 2; ++n) {
            if (n == 1 && !have2) break;              // wave-uniform skip
            const int tjn = n ? tj1 : tj0;
            const bool diagT = (ti == tjn);
            #pragma unroll
            for (int tt = 0; tt < 4; ++tt) {
                const int col = tt * 16 + lr;
                #pragma unroll
                for (int i = 0; i < 4; ++i) {
                    const int row = wave * 16 + q * 4 + i;
                    float x = fmaxf(acc[n][tt][i], 0.f);
                    // tanh(x), x>=0: 1 - 2/(e^{2x}+1); exp->inf saturates to 1
                    float e = __expf(2.f * x);
                    float v = 1.f - 2.f * __builtin_amdgcn_rcpf(e + 1.f);
                    if (diagT && (row == col)) v += 0.5f;
                    Ct[row][col] = v;
                }
            }
            // in-wave LDS ordering via lgkmcnt; wave-private rows, no sync.
            // Full-line stores: 8 rows x 128 B per instruction.
            const int rs = lane >> 3;                 // 0..7
            #pragma unroll
            for (int rh = 0; rh < 2; ++rh) {
                const int r_loc = wave * 16 + rh * 8 + rs;
                float* dst = out + (size_t)b * M_NODES * M_NODES
                                 + (size_t)(ti * TILE + r_loc) * M_NODES
                                 + tjn * TILE;
                #pragma unroll
                for (int u = 0; u < 2; ++u) {
                    const int c4 = (lane & 7) * 4 + 32 * u;
                    *(float4*)(dst + c4) = *(const float4*)&Ct[r_loc][c4];
                }
            }
        }
    }
}

extern "C" void kernel_launch(void* const* d_in, const int* in_sizes, int n_in,
                              void* d_out, int out_size, void* d_ws, size_t ws_size,
                              hipStream_t stream) {
    const float* sp = (const float*)d_in[0];   // [16, 2048, 64] fp32
    const float* tp = (const float*)d_in[1];   // [16, 64, 64]   fp32
    float* out = (float*)d_out;                // [16, 2112, 2112] fp32

    dim3 grid(TOTAL_WGS);                      // 1496; 6 tiles per WG
    dim3 block(256);
    hipLaunchKernelGGL(gram_tanh_mfma, grid, block, 0, stream, sp, tp, out);
}

// Round 11
// 287.568 us; speedup vs baseline: 1.1887x; 1.0067x over previous
//
#include <hip/hip_runtime.h>
#include <hip/hip_fp16.h>

// adj[b] = tanh(relu(E_b @ E_b^T)) + 0.5*I
// E_b = concat(spatial[b] (2048x64), temporal[b] (64x64)) fp32 -> fp16 MFMA,
// fp32 accumulate. Output: [16, 2112, 2112] fp32.
// R17 = R16 with the compile fix: __builtin_nontemporal_store requires a
// native clang vector (ext_vector_type), not HIP's float4 class; store via
// f32x4. Theory unchanged (untested): per-tile cost ~9.2 us is invariant to
// WG count / tiles-per-WG / barriers / store width / occupancy (R6..R15);
// duplicate-value tiles (R14 pass 1, L2 write HITS) cost ~40% less -> the
// WRITE STREAM is the expensive part (2.8 TB/s vs fill's 6.4). Writes stream
// THROUGH the 4 MB/XCD L2, thrashing the staging inputs (8.6 MB unique,
// 431 MB re-read) out of L2; reads then contend with writes on the L3/HBM
// path: (431+285) MB / 6.4 TB/s = 112 us = measured kernel time.
// Fix under test: nt full-line stores (stream/evict-first) keep the output
// out of L2 so inputs stay L2-resident. SINGLE variable vs R13 (278.8).

#define B_BATCH   16
#define N_SPATIAL 2048
#define T_TEMP    64
#define M_NODES   2112     // 33 * 64
#define D_FEAT    64
#define TILE      64
#define LDSK      72       // fp16 k-stride (+8 pad)
#define CSTR      68       // fp32 epilogue tile stride (+4 pad)

// per batch: 33 ti strips x 17 tj-groups (16 groups of 2 tiles + 1 of 1)
#define GROUPS_PER_STRIP 17
#define WGS_PER_BATCH    (33 * GROUPS_PER_STRIP)   // 561
#define TOTAL_WGS        (WGS_PER_BATCH * B_BATCH) // 8976 = 8 * 1122
#define WGS_PER_XCD      (TOTAL_WGS / 8)           // 1122 = 2 batches

typedef _Float16 f16x8 __attribute__((ext_vector_type(8)));
typedef float    f32x4 __attribute__((ext_vector_type(4)));

__device__ __forceinline__ f16x8 cvt2(const float4* p) {
    float4 a = p[0], c = p[1];
    f16x8 h;
    h[0] = (_Float16)a.x; h[1] = (_Float16)a.y;
    h[2] = (_Float16)a.z; h[3] = (_Float16)a.w;
    h[4] = (_Float16)c.x; h[5] = (_Float16)c.y;
    h[6] = (_Float16)c.z; h[7] = (_Float16)c.w;
    return h;
}

__global__ __launch_bounds__(256, 3)
void gram_tanh_mfma(const float* __restrict__ sp,
                    const float* __restrict__ tp,
                    float* __restrict__ out)
{
    // ---- XCD-aware decode: wg lin -> XCD (lin&7, round-robin dispatch);
    // XCD k owns local ids [0,1122) = batches 2k,2k+1, tj fastest.
    const int lin = blockIdx.x;
    const int xcd = lin & 7;
    const int l   = lin >> 3;            // 0..1121
    const int bo  = l / WGS_PER_BATCH;   // 0,1
    const int rr  = l - bo * WGS_PER_BATCH;
    const int ti  = rr / GROUPS_PER_STRIP;          // 0..32
    const int g   = rr - ti * GROUPS_PER_STRIP;     // 0..16
    const int b   = 2 * xcd + bo;
    const int tj0 = 2 * g;
    const bool have2 = (tj0 + 1 < 33);
    const int tj1 = have2 ? tj0 + 1 : 32;           // clamp (g==16 -> dup of tj0)

    __shared__ __align__(16) _Float16 As[TILE][LDSK];       //  9216 B
    __shared__ __align__(16) _Float16 Bs[2][TILE][LDSK];    // 18432 B
    __shared__ __align__(16) float    Ct[TILE][CSTR];       // 17408 B  -> 45056 B

    const int tid = threadIdx.x;

    // ---- stage + convert fp32 -> fp16: row = tid>>2, 16 consecutive k ----
    {
        const int row = tid >> 2;
        const int kb  = (tid & 3) * 16;
        const float* srcA = (ti < 32)
            ? sp + ((size_t)b * N_SPATIAL + (size_t)ti * TILE) * D_FEAT
            : tp + (size_t)b * T_TEMP * D_FEAT;
        const float* srcB0 = (tj0 < 32)
            ? sp + ((size_t)b * N_SPATIAL + (size_t)tj0 * TILE) * D_FEAT
            : tp + (size_t)b * T_TEMP * D_FEAT;
        const float* srcB1 = (tj1 < 32)
            ? sp + ((size_t)b * N_SPATIAL + (size_t)tj1 * TILE) * D_FEAT
            : tp + (size_t)b * T_TEMP * D_FEAT;
        const float4* pa  = (const float4*)(srcA  + (size_t)row * D_FEAT + kb);
        const float4* pb0 = (const float4*)(srcB0 + (size_t)row * D_FEAT + kb);
        const float4* pb1 = (const float4*)(srcB1 + (size_t)row * D_FEAT + kb);

        *(f16x8*)&As[row][kb]        = cvt2(pa);
        *(f16x8*)&As[row][kb + 8]    = cvt2(pa + 2);
        *(f16x8*)&Bs[0][row][kb]     = cvt2(pb0);
        *(f16x8*)&Bs[0][row][kb + 8] = cvt2(pb0 + 2);
        *(f16x8*)&Bs[1][row][kb]     = cvt2(pb1);
        *(f16x8*)&Bs[1][row][kb + 8] = cvt2(pb1 + 2);
    }
    __syncthreads();   // the ONLY barrier

    // ---- MFMA: wave w -> rows [16w,16w+16) x 2 sub-tiles of 64 cols ----
    const int wave = tid >> 6;
    const int lane = tid & 63;
    const int lr   = lane & 15;   // m (A) / n (B) within 16-tile
    const int q    = lane >> 4;   // quad -> k-slice / C row group

    f32x4 acc[2][4];
    #pragma unroll
    for (int n = 0; n < 2; ++n)
        #pragma unroll
        for (int tt = 0; tt < 4; ++tt) acc[n][tt] = (f32x4){0.f, 0.f, 0.f, 0.f};

    #pragma unroll
    for (int s = 0; s < 2; ++s) {                 // K = 64 = 2 x 32
        f16x8 afrag = *(const f16x8*)&As[wave * 16 + lr][s * 32 + q * 8];
        #pragma unroll
        for (int n = 0; n < 2; ++n) {
            #pragma unroll
            for (int tt = 0; tt < 4; ++tt) {
                f16x8 bfrag = *(const f16x8*)&Bs[n][tt * 16 + lr][s * 32 + q * 8];
                acc[n][tt] = __builtin_amdgcn_mfma_f32_16x16x32_f16(afrag, bfrag, acc[n][tt], 0, 0, 0);
            }
        }
    }

    // ---- per sub-tile: tanh(relu)+diag -> wave-private Ct slice -> stores ----
    // Wave w only touches Ct rows [16w,16w+16): no cross-wave sync needed.
    #pragma unroll
    for (int n = 0; n < 2; ++n) {
        if (n == 1 && !have2) break;              // wave-uniform skip (dup tile)
        const int tjn = n ? tj1 : tj0;
        const bool diagT = (ti == tjn);
        #pragma unroll
        for (int tt = 0; tt < 4; ++tt) {
            const int col = tt * 16 + lr;
            #pragma unroll
            for (int i = 0; i < 4; ++i) {
                const int row = wave * 16 + q * 4 + i;
                float x = fmaxf(acc[n][tt][i], 0.f);
                // tanh(x), x>=0: 1 - 2/(e^{2x}+1); exp->inf saturates to 1
                float e = __expf(2.f * x);
                float v = 1.f - 2.f * __builtin_amdgcn_rcpf(e + 1.f);
                if (diagT && (row == col)) v += 0.5f;
                Ct[row][col] = v;
            }
        }
        // in-wave LDS WAR/RAW ordering via lgkmcnt; no __syncthreads.
        // NONTEMPORAL full-line stores: 8 rows x 128 B per instruction,
        // streamed past L2 so staging inputs stay L2-resident.
        // (builtin needs a native clang vector type -> f32x4, not float4)
        const int rs = lane >> 3;                 // 0..7 row within half-slice
        #pragma unroll
        for (int rh = 0; rh < 2; ++rh) {
            const int r_loc = wave * 16 + rh * 8 + rs;
            float* dst = out + (size_t)b * M_NODES * M_NODES
                             + (size_t)(ti * TILE + r_loc) * M_NODES
                             + tjn * TILE;
            #pragma unroll
            for (int u = 0; u < 2; ++u) {
                const int c4 = (lane & 7) * 4 + 32 * u;   // float offset 0..60
                const f32x4 v = *(const f32x4*)&Ct[r_loc][c4];
                __builtin_nontemporal_store(v, (f32x4*)(dst + c4));
            }
        }
    }
}

extern "C" void kernel_launch(void* const* d_in, const int* in_sizes, int n_in,
                              void* d_out, int out_size, void* d_ws, size_t ws_size,
                              hipStream_t stream) {
    const float* sp = (const float*)d_in[0];   // [16, 2048, 64] fp32
    const float* tp = (const float*)d_in[1];   // [16, 64, 64]   fp32
    float* out = (float*)d_out;                // [16, 2112, 2112] fp32

    dim3 grid(TOTAL_WGS);                      // 8976; kernel does XCD decode
    dim3 block(256);
    hipLaunchKernelGGL(gram_tanh_mfma, grid, block, 0, stream, sp, tp, out);
}